// Round 7
// baseline (86.663 us; speedup 1.0000x reference)
//
#include <hip/hip_runtime.h>
#include <hip/hip_bf16.h>

// B=8, T=4096, C=32, D=64. Causal, no 1/sqrt(D) scaling.
constexpr int Bc = 8;
constexpr int Tt = 4096;
constexpr int Dd = 64;

typedef __attribute__((ext_vector_type(8))) short short8;   // 8 bf16 = 4 VGPRs
typedef __attribute__((ext_vector_type(4))) float floatx4;  // MFMA C/D frag
typedef __attribute__((ext_vector_type(4))) __fp16 half4;   // 4 f16 = 2 VGPRs
typedef __attribute__((ext_vector_type(2))) __fp16 half2v;
typedef uint4   __attribute__((may_alias)) uint4_a;
typedef uint2   __attribute__((may_alias)) uint2_a;
typedef short8  __attribute__((may_alias)) short8_a;
typedef ushort4 __attribute__((may_alias)) ushort4_a;
typedef float4  __attribute__((may_alias)) float4_a;
typedef half4   __attribute__((may_alias)) half4_a;

#define MFMA16(A, B, C)  __builtin_amdgcn_mfma_f32_16x16x32_bf16(A, B, C, 0, 0, 0)
#define MFMAH16(A, B, C) __builtin_amdgcn_mfma_f32_16x16x16f16(A, B, C, 0, 0, 0)
constexpr float LOG2E = 1.4426950408889634f;

// Workspace layout (bytes). Total ~6 MB + 4 KB (ws is 256 MB).
constexpr size_t XB_OFF = 0;                   // xb : [B*T][32] bf16, 64 B rows
constexpr size_t YB_OFF = (size_t)2 << 20;     // Yb : [B*T][32] bf16, 64 B rows
constexpr size_t XT_OFF = (size_t)4 << 20;     // xt : [B*256 chunk][16 ln][4 qd] 16B granules
constexpr size_t WV_OFF = (size_t)6 << 20;     // Wvb: [64][32] bf16 (Wv^T rows)

// ---- fast fp32 -> bf16: round-half-up (u + 0x8000), pack 2 via v_perm ----
__device__ __forceinline__ unsigned rnd16(float x) {
    unsigned u; __builtin_memcpy(&u, &x, 4); return u + 0x8000u;
}
__device__ __forceinline__ unsigned pk_bf2(float lo, float hi) {
    return __builtin_amdgcn_perm(rnd16(hi), rnd16(lo), 0x07060302);
}
__device__ __forceinline__ ushort4 pack4(floatx4 d) {
    union { unsigned u[2]; ushort4 v; } r;
    r.u[0] = pk_bf2(d[0], d[1]);
    r.u[1] = pk_bf2(d[2], d[3]);
    return r.v;
}
__device__ __forceinline__ short8 cvt8(float4 a, float4 b) {
    union { unsigned u[4]; short8 s; } r;
    r.u[0] = pk_bf2(a.x, a.y);
    r.u[1] = pk_bf2(a.z, a.w);
    r.u[2] = pk_bf2(b.x, b.y);
    r.u[3] = pk_bf2(b.z, b.w);
    return r.s;
}

// ---------------------------------------------------------------------------
// R20 prepass: SAME work as R19, but block decomposition remapped for XCD-L2
// locality: block bi handles batch b = bi&7, chunk ch = bi>>3 (was b=bi>>6,
// ch=bi&63). Under round-robin workgroup placement, XCD = bi%8 = b, so every
// batch-b tile is WRITTEN on XCD b's L2 -- the same XCD where attn's batch-b
// blocks (idx&7 == b) READ them. R19's mismatch sent nearly all fragment
// reads to L3 (~266 MB at shared-BW/latency ~= the whole 21 us attn time).
// Per-batch working set (xb+Yb+xt ~= 768 KB) fits the 4 MB XCD L2.
// ---------------------------------------------------------------------------
__global__ __launch_bounds__(256) void prep_kernel(
    const float* __restrict__ x,
    const float* __restrict__ Wk, const float* __restrict__ Wq,
    const float* __restrict__ Wv,
    char* __restrict__ ws)
{
    __shared__ uint4 sG[128];    // 2 KB: G^T [c'][c] bf16
    __shared__ float sX[2048];   // 8 KB: fp32 slab [64 row][32 c]

    const int bi = blockIdx.x;
    const int b = bi & 7, ch = bi >> 3;          // XCD-aligned decomposition
    const int tid = threadIdx.x;
    const int wave = tid >> 6, lane = tid & 63;
    const int ln15 = lane & 15, quad = lane >> 4;
    const size_t bT = (size_t)b * Tt;
    const int r0 = ch * 64;

    const int lr = wave * 16 + ln15;
    const float* xp = x + (bT + r0 + lr) * 32 + quad * 8;
    float4 pX0 = ((const float4_a*)xp)[0];
    float4 pX1 = ((const float4_a*)xp)[1];
    *(float4_a*)(&sX[lr * 32 + quad * 8])     = pX0;
    *(float4_a*)(&sX[lr * 32 + quad * 8 + 4]) = pX1;

    if (wave == 0) {
        floatx4 gC[2][2];
        #pragma unroll
        for (int mt = 0; mt < 2; ++mt)
            #pragma unroll
            for (int nt = 0; nt < 2; ++nt) gC[mt][nt] = (floatx4){0.f,0.f,0.f,0.f};
        #pragma unroll
        for (int kt = 0; kt < 2; ++kt) {
            short8 aG[2], bG[2];
            #pragma unroll
            for (int mt = 0; mt < 2; ++mt) {
                const float* qp = Wq + (ln15 + 16*mt)*64 + 32*kt + quad*8;
                float4 a = ((const float4_a*)qp)[0], bb = ((const float4_a*)qp)[1];
                a.x*=LOG2E; a.y*=LOG2E; a.z*=LOG2E; a.w*=LOG2E;
                bb.x*=LOG2E; bb.y*=LOG2E; bb.z*=LOG2E; bb.w*=LOG2E;
                aG[mt] = cvt8(a, bb);
                const float* kp = Wk + (ln15 + 16*mt)*64 + 32*kt + quad*8;
                bG[mt] = cvt8(((const float4_a*)kp)[0], ((const float4_a*)kp)[1]);
            }
            #pragma unroll
            for (int mt = 0; mt < 2; ++mt)
                #pragma unroll
                for (int nt = 0; nt < 2; ++nt)
                    gC[mt][nt] = MFMA16(aG[mt], bG[nt], gC[mt][nt]);
        }
        unsigned short* sGh = (unsigned short*)sG;
        #pragma unroll
        for (int mt = 0; mt < 2; ++mt)
            #pragma unroll
            for (int nt = 0; nt < 2; ++nt)
                *(ushort4_a*)(sGh + (16*nt + ln15)*32 + 16*mt + quad*4)
                    = pack4(gC[mt][nt]);
    }
    __syncthreads();

    // xb: bf16 [row][c]
    union { unsigned u[4]; uint4 v; } xu;
    xu.u[0] = pk_bf2(pX0.x, pX0.y); xu.u[1] = pk_bf2(pX0.z, pX0.w);
    xu.u[2] = pk_bf2(pX1.x, pX1.y); xu.u[3] = pk_bf2(pX1.z, pX1.w);
    *(uint4_a*)(ws + XB_OFF + (size_t)(bT + r0 + lr) * 64 + quad * 16) = xu.v;

    // Y = x·G: 2 MFMA per wave; bf16 [q][yc] rows
    {
        short8 xq = cvt8(pX0, pX1);
        unsigned short* yb = (unsigned short*)(ws + YB_OFF);
        #pragma unroll
        for (int mt = 0; mt < 2; ++mt) {
            union { uint4 u; short8 s; } g;
            g.u = sG[(16*mt + ln15)*4 + quad];
            floatx4 d = (floatx4){0.f,0.f,0.f,0.f};
            d = MFMA16(g.s, xq, d);   // col=q=ln15, row=yc=16mt+quad*4+r
            *(ushort4_a*)(yb + (size_t)(bT + r0 + lr) * 32 + 16*mt + quad*4)
                = pack4(d);
        }
    }

    // xt: one thread per 16B granule (4 kc x 16 ln x 4 qd = 256, bijective)
    {
        const int kc = tid >> 6;            // 16-key chunk 0..3
        const int ln = (tid >> 2) & 15;     // c' low index
        const int qd = tid & 3;             // key quad
        const int kr = kc*16 + qd*4;
        union { unsigned u[4]; uint4 q; } x4;
        union { half2v h; unsigned u; } p0, p1, p2, p3;
        p0.h = __builtin_amdgcn_cvt_pkrtz(sX[(kr+0)*32 + ln],      sX[(kr+1)*32 + ln]);
        p1.h = __builtin_amdgcn_cvt_pkrtz(sX[(kr+2)*32 + ln],      sX[(kr+3)*32 + ln]);
        p2.h = __builtin_amdgcn_cvt_pkrtz(sX[(kr+0)*32 + ln + 16], sX[(kr+1)*32 + ln + 16]);
        p3.h = __builtin_amdgcn_cvt_pkrtz(sX[(kr+2)*32 + ln + 16], sX[(kr+3)*32 + ln + 16]);
        x4.u[0] = p0.u; x4.u[1] = p1.u; x4.u[2] = p2.u; x4.u[3] = p3.u;
        *(uint4_a*)(ws + XT_OFF + (size_t)(b*256 + ch*4 + kc) * 1024
                    + ln*64 + qd*16) = x4.q;
    }

    // Wvb: Wv^T bf16 [d][c'] (block 0, wave 2 only)
    if (bi == 0 && wave == 2) {
        const int d = lane;
        unsigned short* wvb = (unsigned short*)(ws + WV_OFF);
        float v[32];
        #pragma unroll
        for (int c2 = 0; c2 < 32; ++c2) v[c2] = Wv[c2*64 + d];
        #pragma unroll
        for (int i2 = 0; i2 < 16; ++i2)
            ((unsigned*)(wvb + d*32))[i2] = pk_bf2(v[2*i2], v[2*i2+1]);
    }
}

// ---------------------------------------------------------------------------
// R20 main == R19 main (verified passing). One-wave-per-tile body, 4-way
// split-K, 4 blocks/CU fully resident (4 waves/SIMD), no spills (VGPR ~100),
// balanced bijective qt map, 8 coalesced 1KB loads per body, zero barriers
// in the k-loop. The round's single variable is prep-side XCD alignment.
// ---------------------------------------------------------------------------
__global__ __launch_bounds__(256, 4) void attn_kernel(
    const char* __restrict__ ws, float* __restrict__ out)
{
    __shared__ float4 sZm[2][4][2][64];  // 16 KB [nt][kg][comp][lane]
    __shared__ float  sLm[2][4][64];     //  2 KB [nt][kg][lane]
    __shared__ uint4  sB4[4][64];        //  4 KB per-wave Z pack region

    const int idx = blockIdx.x;
    const int b = idx & 7;               // batch == XCD slot (matches prep now)
    const int j = idx >> 3;              // 0..127
    const int m = j >> 5, c5 = j & 31;
    const int qt = (m & 1) ? (32*m + 31 - c5) : (32*m + c5);  // balanced, bijective
    const int tid = threadIdx.x;
    const int kg = tid >> 6, lane = tid & 63;   // split-K group 0..3
    const int ln15 = lane & 15, quad = lane >> 4;
    const size_t bT = (size_t)b * Tt;
    const int q0 = qt * 32;
    const int K = qt >> 1;               // last k-tile index

    const char* xbB = ws + XB_OFF + bT * 64;
    const char* xtB = ws + XT_OFF + (size_t)b * (256 * 1024);
    const int aOff = ln15 * 64 + quad * 16;  // shared by S A-frag and xt granule

    // Y B-frags for the 2 q-subtiles (n=q=ln15, k=yc=quad*8+j), loop-invariant
    short8 bq[2];
    #pragma unroll
    for (int nt = 0; nt < 2; ++nt) {
        union { uint4 u4; short8 s; } t0;
        t0.u4 = *(const uint4_a*)(ws + YB_OFF
                 + (size_t)(bT + q0 + 16*nt + ln15) * 64 + quad * 16);
        bq[nt] = t0.s;
    }

    floatx4 z4[2][2];   // Z^T acc per nt: (col=q=ln15, row=c'=16mt+quad*4+r)
    float lq[2];
    #pragma unroll
    for (int nt = 0; nt < 2; ++nt) {
        z4[nt][0] = (floatx4){0.f,0.f,0.f,0.f};
        z4[nt][1] = (floatx4){0.f,0.f,0.f,0.f};
        lq[nt] = 0.f;
    }

    short8 aA[4], aB4[4];   // double-buffered S A-frags

    auto LDA = [&](int k, short8* a) {
        const char* p = xbB + (size_t)k * 4096 + aOff;
        #pragma unroll
        for (int t = 0; t < 4; ++t)
            a[t] = *(const short8_a*)(p + t * 1024);
    };

    auto BODY = [&](int kt, const short8* a) {
        // PV A-frag pairs: ONE uint4 each (lo half = c'=ln15, hi = ln15+16)
        const char* px = xtB + (size_t)kt * 4096 + aOff;
        union { uint4 u4; half4 h[2]; } xa[4];
        #pragma unroll
        for (int t = 0; t < 4; ++t)
            xa[t].u4 = *(const uint4_a*)(px + t * 1024);
        __builtin_amdgcn_sched_barrier(0);   // pin loads above the MFMA storm
        #pragma unroll
        for (int nt = 0; nt < 2; ++nt) {
            // S^T = x_k · Y^T : 4 MFMA (K=32) for this q-subtile
            floatx4 s4[4];
            #pragma unroll
            for (int t = 0; t < 4; ++t) {
                floatx4 c0 = (floatx4){0.f,0.f,0.f,0.f};
                s4[t] = MFMA16(a[t], bq[nt], c0);
            }
            // p = exp2(s) in-register (mask only the diagonal k-tile)
            if (kt == K) {   // wave-uniform branch
                const int qrow = q0 + 16*nt + ln15;
                #pragma unroll
                for (int t = 0; t < 4; ++t) {
                    const int keyb = kt*64 + 16*t + quad*4;
                    #pragma unroll
                    for (int r = 0; r < 4; ++r) {
                        float p = (keyb + r <= qrow)
                                  ? __builtin_amdgcn_exp2f(s4[t][r]) : 0.f;
                        s4[t][r] = p; lq[nt] += p;
                    }
                }
            } else {
                #pragma unroll
                for (int t = 0; t < 4; ++t)
                    #pragma unroll
                    for (int r = 0; r < 4; ++r) {
                        float p = __builtin_amdgcn_exp2f(s4[t][r]);
                        s4[t][r] = p; lq[nt] += p;
                    }
            }
            // Z^T += x^T · P^T : 8 mfma f16 K=16, P direct from registers
            #pragma unroll
            for (int t = 0; t < 4; ++t) {
                union { half2v h2[2]; half4 h4; } pb;
                pb.h2[0] = __builtin_amdgcn_cvt_pkrtz(s4[t][0], s4[t][1]);
                pb.h2[1] = __builtin_amdgcn_cvt_pkrtz(s4[t][2], s4[t][3]);
                z4[nt][0] = MFMAH16(xa[t].h[0], pb.h4, z4[nt][0]);
                z4[nt][1] = MFMAH16(xa[t].h[1], pb.h4, z4[nt][1]);
            }
        }
    };

    // ---- barrier-free pipelined k-loop: kt = kg, kg+4, ... <= K ----
    int kt = kg;
    if (kt <= K) {
        LDA(kt, aA);
        while (true) {
            int kn = kt + 4;
            LDA(kn <= K ? kn : kt, aB4);   // clamped prefetch (in-bounds)
            BODY(kt, aA);
            if (kn > K) break;
            kt = kn; kn = kt + 4;
            LDA(kn <= K ? kn : kt, aA);
            BODY(kt, aB4);
            if (kn > K) break;
            kt = kn;
        }
    }

    // ---- dump 4 split-K partials to LDS (single barrier) ----
    #pragma unroll
    for (int nt = 0; nt < 2; ++nt) {
        sZm[nt][kg][0][lane] = make_float4(z4[nt][0][0], z4[nt][0][1],
                                           z4[nt][0][2], z4[nt][0][3]);
        sZm[nt][kg][1][lane] = make_float4(z4[nt][1][0], z4[nt][1][1],
                                           z4[nt][1][2], z4[nt][1][3]);
        sLm[nt][kg][lane] = lq[nt];
    }
    __syncthreads();

    // ---- epilogue: wave kg -> subtile nt=kg>>1, d-half th=kg&1 ----
    {
        const int nt = kg >> 1, th = kg & 1;
        float4 zm0 = make_float4(0.f,0.f,0.f,0.f);
        float4 zm1 = make_float4(0.f,0.f,0.f,0.f);
        float l = 0.f;
        #pragma unroll
        for (int g = 0; g < 4; ++g) {
            float4 a0 = sZm[nt][g][0][lane];
            float4 a1 = sZm[nt][g][1][lane];
            zm0.x+=a0.x; zm0.y+=a0.y; zm0.z+=a0.z; zm0.w+=a0.w;
            zm1.x+=a1.x; zm1.y+=a1.y; zm1.z+=a1.z; zm1.w+=a1.w;
            l += sLm[nt][g][lane];
        }
        l += __shfl_xor(l, 16);    // quads hold disjoint key subsets
        l += __shfl_xor(l, 32);
        const float inv = 1.f / l;

        // Wv^T A-frags for this wave's half of d (L2-hot prepass buffer)
        const unsigned short* wvb = (const unsigned short*)(ws + WV_OFF);
        short8 wv_f[2];
        #pragma unroll
        for (int tt = 0; tt < 2; ++tt) {
            const int t = 2*th + tt;
            union { uint4 u4; short8 s; } w0;
            w0.u4 = *(const uint4_a*)(wvb + (16*t + ln15) * 32 + quad * 8);
            wv_f[tt] = w0.s;
        }
        // pack merged Z as bf16 [q(16)][c'(32)]; same-wave LDS round-trip
        unsigned short* sZb = (unsigned short*)&sB4[kg][0];
        floatx4 zv0 = (floatx4){zm0.x, zm0.y, zm0.z, zm0.w};
        floatx4 zv1 = (floatx4){zm1.x, zm1.y, zm1.z, zm1.w};
        *(ushort4_a*)(sZb + ln15*32 + quad*4)      = pack4(zv0);
        *(ushort4_a*)(sZb + ln15*32 + 16 + quad*4) = pack4(zv1);
        union { uint4 u4; short8 s; } zb;
        zb.u4 = sB4[kg][ln15*4 + quad];
        // O^T = Wv^T · Z^T : 2 MFMA (K=32); col=q=ln15, row=d=16t+quad*4+r
        const int qrow = q0 + 16*nt + ln15;
        #pragma unroll
        for (int tt = 0; tt < 2; ++tt) {
            const int t = 2*th + tt;
            floatx4 o = (floatx4){0.f,0.f,0.f,0.f};
            o = MFMA16(wv_f[tt], zb.s, o);
            *(float4_a*)(out + (bT + (size_t)qrow) * Dd + 16*t + quad*4)
                = make_float4(o[0]*inv, o[1]*inv, o[2]*inv, o[3]*inv);
        }
    }
}

// ---------------------------------------------------------------------------
extern "C" void kernel_launch(void* const* d_in, const int* in_sizes, int n_in,
                              void* d_out, int out_size, void* d_ws, size_t ws_size,
                              hipStream_t stream)
{
    const float* x  = (const float*)d_in[0];
    const float* Wk = (const float*)d_in[1];   // setup_inputs order: x, Wk, Wq, Wv
    const float* Wq = (const float*)d_in[2];
    const float* Wv = (const float*)d_in[3];
    float* out = (float*)d_out;

    // Prepass: 512 blocks x 256 thr; block bi -> (batch bi&7, chunk bi>>3)
    // so writes land on the XCD-L2 where attn's same-batch blocks read.
    prep_kernel<<<512, 256, 0, stream>>>(x, Wk, Wq, Wv, (char*)d_ws);
    // Main: 1024 blocks (4/CU, fully resident, b==XCD), 256 thr, 22 KB LDS.
    attn_kernel<<<Bc * 128, 256, 0, stream>>>((const char*)d_ws, out);
}

// Round 9
// 86.322 us; speedup vs baseline: 1.0039x; 1.0039x over previous
//
#include <hip/hip_runtime.h>
#include <hip/hip_bf16.h>

// B=8, T=4096, C=32, D=64. Causal, no 1/sqrt(D) scaling.
constexpr int Bc = 8;
constexpr int Tt = 4096;
constexpr int Dd = 64;

typedef __attribute__((ext_vector_type(8))) short short8;   // 8 bf16 = 4 VGPRs
typedef __attribute__((ext_vector_type(4))) float floatx4;  // MFMA C/D frag
typedef __attribute__((ext_vector_type(4))) __fp16 half4;   // 4 f16 = 2 VGPRs
typedef __attribute__((ext_vector_type(2))) __fp16 half2v;
typedef uint4   __attribute__((may_alias)) uint4_a;
typedef uint2   __attribute__((may_alias)) uint2_a;
typedef short8  __attribute__((may_alias)) short8_a;
typedef ushort4 __attribute__((may_alias)) ushort4_a;
typedef float4  __attribute__((may_alias)) float4_a;
typedef half4   __attribute__((may_alias)) half4_a;

#define MFMA16(A, B, C)  __builtin_amdgcn_mfma_f32_16x16x32_bf16(A, B, C, 0, 0, 0)
#define MFMAH16(A, B, C) __builtin_amdgcn_mfma_f32_16x16x16f16(A, B, C, 0, 0, 0)
constexpr float LOG2E = 1.4426950408889634f;

// Workspace layout (bytes). Total ~6 MB + 4 KB (ws is 256 MB).
constexpr size_t XB_OFF = 0;                   // xb : [B*T][32] bf16, 64 B rows
constexpr size_t YB_OFF = (size_t)2 << 20;     // Yb : [B*T][32] bf16, 64 B rows
constexpr size_t XT_OFF = (size_t)4 << 20;     // xt : [B*256 chunk][16 ln][4 qd] 16B granules
constexpr size_t WV_OFF = (size_t)6 << 20;     // Wvb: [64][32] bf16 (Wv^T rows)

// ---- fast fp32 -> bf16: round-half-up (u + 0x8000), pack 2 via v_perm ----
__device__ __forceinline__ unsigned rnd16(float x) {
    unsigned u; __builtin_memcpy(&u, &x, 4); return u + 0x8000u;
}
__device__ __forceinline__ unsigned pk_bf2(float lo, float hi) {
    return __builtin_amdgcn_perm(rnd16(hi), rnd16(lo), 0x07060302);
}
__device__ __forceinline__ ushort4 pack4(floatx4 d) {
    union { unsigned u[2]; ushort4 v; } r;
    r.u[0] = pk_bf2(d[0], d[1]);
    r.u[1] = pk_bf2(d[2], d[3]);
    return r.v;
}
__device__ __forceinline__ short8 cvt8(float4 a, float4 b) {
    union { unsigned u[4]; short8 s; } r;
    r.u[0] = pk_bf2(a.x, a.y);
    r.u[1] = pk_bf2(a.z, a.w);
    r.u[2] = pk_bf2(b.x, b.y);
    r.u[3] = pk_bf2(b.z, b.w);
    return r.s;
}

// ---------------------------------------------------------------------------
// R22 prepass: restructured for minimal wall time (output bytes IDENTICAL to
// R20's proven prep). 1024 blocks x 256 thr = 4 blocks/CU, whole grid
// resident in one shot; one 32-row slab per block (b = bi&7 keeps XCD
// alignment). Wave roles:
//   waves 0-1: frag-layout slab load (32B/lane) -> sX; wave 0 also computes
//              G = (log2e Wq)·Wk^T -> sG (runs while x loads are in flight);
//              pre-barrier xb store; post-barrier Y = x·G MFMA + store.
//   wave 2 of block 0: Wv^T -> wvb (fills its pre-barrier idle).
//   waves 2-3: post-barrier xt transpose granules from sX (one 16B granule
//              per thread: 2 kc x 16 ln x 4 qd = 128 = their thread count).
// Exactly ONE __syncthreads; no idle-wave G wait (R20 had 3 waves parked
// behind wave0's G); critical path ~1.2K cyc vs R20's ~2.5K at 2x the
// block parallelism.
// ---------------------------------------------------------------------------
__global__ __launch_bounds__(256) void prep_kernel(
    const float* __restrict__ x,
    const float* __restrict__ Wk, const float* __restrict__ Wq,
    const float* __restrict__ Wv,
    char* __restrict__ ws)
{
    __shared__ float sX[1024];   // 4 KB: fp32 slab [32 row][32 c]
    __shared__ uint4 sG[128];    // 2 KB: G^T [c'][c] bf16

    const int bi = blockIdx.x;
    const int b = bi & 7, ch = bi >> 3;          // XCD-aligned; ch 0..127
    const int tid = threadIdx.x;
    const int wave = tid >> 6, lane = tid & 63;
    const int ln15 = lane & 15, quad = lane >> 4;
    const size_t bT = (size_t)b * Tt;
    const int r0 = ch * 32;

    if (wave < 2) {
        const int lr = wave * 16 + ln15;         // 0..31
        const float* xp = x + (bT + r0 + lr) * 32 + quad * 8;
        float4 pX0 = ((const float4_a*)xp)[0];
        float4 pX1 = ((const float4_a*)xp)[1];
        *(float4_a*)(&sX[lr * 32 + quad * 8])     = pX0;
        *(float4_a*)(&sX[lr * 32 + quad * 8 + 4]) = pX1;

        if (wave == 0) {
            // G = (log2e Wq)·Wk^T [32x32] -> sG (verbatim R20 math)
            floatx4 gC[2][2];
            #pragma unroll
            for (int mt = 0; mt < 2; ++mt)
                #pragma unroll
                for (int nt = 0; nt < 2; ++nt) gC[mt][nt] = (floatx4){0.f,0.f,0.f,0.f};
            #pragma unroll
            for (int kt = 0; kt < 2; ++kt) {
                short8 aG[2], bG[2];
                #pragma unroll
                for (int mt = 0; mt < 2; ++mt) {
                    const float* qp = Wq + (ln15 + 16*mt)*64 + 32*kt + quad*8;
                    float4 a = ((const float4_a*)qp)[0], bb = ((const float4_a*)qp)[1];
                    a.x*=LOG2E; a.y*=LOG2E; a.z*=LOG2E; a.w*=LOG2E;
                    bb.x*=LOG2E; bb.y*=LOG2E; bb.z*=LOG2E; bb.w*=LOG2E;
                    aG[mt] = cvt8(a, bb);
                    const float* kp = Wk + (ln15 + 16*mt)*64 + 32*kt + quad*8;
                    bG[mt] = cvt8(((const float4_a*)kp)[0], ((const float4_a*)kp)[1]);
                }
                #pragma unroll
                for (int mt = 0; mt < 2; ++mt)
                    #pragma unroll
                    for (int nt = 0; nt < 2; ++nt)
                        gC[mt][nt] = MFMA16(aG[mt], bG[nt], gC[mt][nt]);
            }
            unsigned short* sGh = (unsigned short*)sG;
            #pragma unroll
            for (int mt = 0; mt < 2; ++mt)
                #pragma unroll
                for (int nt = 0; nt < 2; ++nt)
                    *(ushort4_a*)(sGh + (16*nt + ln15)*32 + 16*mt + quad*4)
                        = pack4(gC[mt][nt]);
        }

        // xb: bf16 [row][c] (pre-barrier; needs only pX)
        union { unsigned u[4]; uint4 v; } xu;
        xu.u[0] = pk_bf2(pX0.x, pX0.y); xu.u[1] = pk_bf2(pX0.z, pX0.w);
        xu.u[2] = pk_bf2(pX1.x, pX1.y); xu.u[3] = pk_bf2(pX1.z, pX1.w);
        *(uint4_a*)(ws + XB_OFF + (size_t)(bT + r0 + lr) * 64 + quad * 16) = xu.v;

        __syncthreads();                 // publishes sX (and sG)

        // Y = x·G: 2 MFMA per wave; bf16 [q][yc] rows (verbatim R20 math)
        short8 xq = cvt8(pX0, pX1);
        unsigned short* yb = (unsigned short*)(ws + YB_OFF);
        #pragma unroll
        for (int mt = 0; mt < 2; ++mt) {
            union { uint4 u; short8 s; } g;
            g.u = sG[(16*mt + ln15)*4 + quad];
            floatx4 d = (floatx4){0.f,0.f,0.f,0.f};
            d = MFMA16(g.s, xq, d);   // col=q=ln15, row=yc=16mt+quad*4+r
            *(ushort4_a*)(yb + (size_t)(bT + r0 + lr) * 32 + 16*mt + quad*4)
                = pack4(d);
        }
    } else {
        // Wv^T bf16 (block 0, wave 2: pre-barrier idle time)
        if (bi == 0 && wave == 2) {
            const int d = lane;
            unsigned short* wvb = (unsigned short*)(ws + WV_OFF);
            float v[32];
            #pragma unroll
            for (int c2 = 0; c2 < 32; ++c2) v[c2] = Wv[c2*64 + d];
            #pragma unroll
            for (int i2 = 0; i2 < 16; ++i2)
                ((unsigned*)(wvb + d*32))[i2] = pk_bf2(v[2*i2], v[2*i2+1]);
        }
        __syncthreads();                 // wait for sX

        // xt: one thread per 16B granule (2 kc x 16 ln x 4 qd = 128 threads)
        const int tid2 = tid - 128;
        const int kc = tid2 >> 6;            // 16-key chunk 0..1
        const int ln = (tid2 >> 2) & 15;     // c' low index
        const int qd = tid2 & 3;             // key quad
        const int kr = kc*16 + qd*4;
        union { unsigned u[4]; uint4 q; } x4;
        union { half2v h; unsigned u; } p0, p1, p2, p3;
        p0.h = __builtin_amdgcn_cvt_pkrtz(sX[(kr+0)*32 + ln],      sX[(kr+1)*32 + ln]);
        p1.h = __builtin_amdgcn_cvt_pkrtz(sX[(kr+2)*32 + ln],      sX[(kr+3)*32 + ln]);
        p2.h = __builtin_amdgcn_cvt_pkrtz(sX[(kr+0)*32 + ln + 16], sX[(kr+1)*32 + ln + 16]);
        p3.h = __builtin_amdgcn_cvt_pkrtz(sX[(kr+2)*32 + ln + 16], sX[(kr+3)*32 + ln + 16]);
        x4.u[0] = p0.u; x4.u[1] = p1.u; x4.u[2] = p2.u; x4.u[3] = p3.u;
        *(uint4_a*)(ws + XT_OFF + (size_t)(b*256 + ch*2 + kc) * 1024
                    + ln*64 + qd*16) = x4.q;
    }
}

// ---------------------------------------------------------------------------
// R22 main == R20 main VERBATIM (passing at 86.7). One-wave-per-tile body,
// 4-way split-K, 4 blocks/CU fully resident, balanced bijective qt map,
// 8x 1KB coalesced loads/body, zero barriers in the k-loop, single-barrier
// LDS merge, per-wave epilogue. This round's only variable is prep.
// ---------------------------------------------------------------------------
__global__ __launch_bounds__(256, 4) void attn_kernel(
    const char* __restrict__ ws, float* __restrict__ out)
{
    __shared__ float4 sZm[2][4][2][64];  // 16 KB [nt][kg][comp][lane]
    __shared__ float  sLm[2][4][64];     //  2 KB [nt][kg][lane]
    __shared__ uint4  sB4[4][64];        //  4 KB per-wave Z pack region

    const int idx = blockIdx.x;
    const int b = idx & 7;               // batch == XCD slot (matches prep)
    const int j = idx >> 3;              // 0..127
    const int m = j >> 5, c5 = j & 31;
    const int qt = (m & 1) ? (32*m + 31 - c5) : (32*m + c5);  // balanced, bijective
    const int tid = threadIdx.x;
    const int kg = tid >> 6, lane = tid & 63;   // split-K group 0..3
    const int ln15 = lane & 15, quad = lane >> 4;
    const size_t bT = (size_t)b * Tt;
    const int q0 = qt * 32;
    const int K = qt >> 1;               // last k-tile index

    const char* xbB = ws + XB_OFF + bT * 64;
    const char* xtB = ws + XT_OFF + (size_t)b * (256 * 1024);
    const int aOff = ln15 * 64 + quad * 16;  // shared by S A-frag and xt granule

    // Y B-frags for the 2 q-subtiles (n=q=ln15, k=yc=quad*8+j), loop-invariant
    short8 bq[2];
    #pragma unroll
    for (int nt = 0; nt < 2; ++nt) {
        union { uint4 u4; short8 s; } t0;
        t0.u4 = *(const uint4_a*)(ws + YB_OFF
                 + (size_t)(bT + q0 + 16*nt + ln15) * 64 + quad * 16);
        bq[nt] = t0.s;
    }

    floatx4 z4[2][2];   // Z^T acc per nt: (col=q=ln15, row=c'=16mt+quad*4+r)
    float lq[2];
    #pragma unroll
    for (int nt = 0; nt < 2; ++nt) {
        z4[nt][0] = (floatx4){0.f,0.f,0.f,0.f};
        z4[nt][1] = (floatx4){0.f,0.f,0.f,0.f};
        lq[nt] = 0.f;
    }

    short8 aA[4], aB4[4];   // double-buffered S A-frags

    auto LDA = [&](int k, short8* a) {
        const char* p = xbB + (size_t)k * 4096 + aOff;
        #pragma unroll
        for (int t = 0; t < 4; ++t)
            a[t] = *(const short8_a*)(p + t * 1024);
    };

    auto BODY = [&](int kt, const short8* a) {
        // PV A-frag pairs: ONE uint4 each (lo half = c'=ln15, hi = ln15+16)
        const char* px = xtB + (size_t)kt * 4096 + aOff;
        union { uint4 u4; half4 h[2]; } xa[4];
        #pragma unroll
        for (int t = 0; t < 4; ++t)
            xa[t].u4 = *(const uint4_a*)(px + t * 1024);
        __builtin_amdgcn_sched_barrier(0);   // pin loads above the MFMA storm
        #pragma unroll
        for (int nt = 0; nt < 2; ++nt) {
            // S^T = x_k · Y^T : 4 MFMA (K=32) for this q-subtile
            floatx4 s4[4];
            #pragma unroll
            for (int t = 0; t < 4; ++t) {
                floatx4 c0 = (floatx4){0.f,0.f,0.f,0.f};
                s4[t] = MFMA16(a[t], bq[nt], c0);
            }
            // p = exp2(s) in-register (mask only the diagonal k-tile)
            if (kt == K) {   // wave-uniform branch
                const int qrow = q0 + 16*nt + ln15;
                #pragma unroll
                for (int t = 0; t < 4; ++t) {
                    const int keyb = kt*64 + 16*t + quad*4;
                    #pragma unroll
                    for (int r = 0; r < 4; ++r) {
                        float p = (keyb + r <= qrow)
                                  ? __builtin_amdgcn_exp2f(s4[t][r]) : 0.f;
                        s4[t][r] = p; lq[nt] += p;
                    }
                }
            } else {
                #pragma unroll
                for (int t = 0; t < 4; ++t)
                    #pragma unroll
                    for (int r = 0; r < 4; ++r) {
                        float p = __builtin_amdgcn_exp2f(s4[t][r]);
                        s4[t][r] = p; lq[nt] += p;
                    }
            }
            // Z^T += x^T · P^T : 8 mfma f16 K=16, P direct from registers
            #pragma unroll
            for (int t = 0; t < 4; ++t) {
                union { half2v h2[2]; half4 h4; } pb;
                pb.h2[0] = __builtin_amdgcn_cvt_pkrtz(s4[t][0], s4[t][1]);
                pb.h2[1] = __builtin_amdgcn_cvt_pkrtz(s4[t][2], s4[t][3]);
                z4[nt][0] = MFMAH16(xa[t].h[0], pb.h4, z4[nt][0]);
                z4[nt][1] = MFMAH16(xa[t].h[1], pb.h4, z4[nt][1]);
            }
        }
    };

    // ---- barrier-free pipelined k-loop: kt = kg, kg+4, ... <= K ----
    int kt = kg;
    if (kt <= K) {
        LDA(kt, aA);
        while (true) {
            int kn = kt + 4;
            LDA(kn <= K ? kn : kt, aB4);   // clamped prefetch (in-bounds)
            BODY(kt, aA);
            if (kn > K) break;
            kt = kn; kn = kt + 4;
            LDA(kn <= K ? kn : kt, aA);
            BODY(kt, aB4);
            if (kn > K) break;
            kt = kn;
        }
    }

    // ---- dump 4 split-K partials to LDS (single barrier) ----
    #pragma unroll
    for (int nt = 0; nt < 2; ++nt) {
        sZm[nt][kg][0][lane] = make_float4(z4[nt][0][0], z4[nt][0][1],
                                           z4[nt][0][2], z4[nt][0][3]);
        sZm[nt][kg][1][lane] = make_float4(z4[nt][1][0], z4[nt][1][1],
                                           z4[nt][1][2], z4[nt][1][3]);
        sLm[nt][kg][lane] = lq[nt];
    }
    __syncthreads();

    // ---- epilogue: wave kg -> subtile nt=kg>>1, d-half th=kg&1 ----
    {
        const int nt = kg >> 1, th = kg & 1;
        float4 zm0 = make_float4(0.f,0.f,0.f,0.f);
        float4 zm1 = make_float4(0.f,0.f,0.f,0.f);
        float l = 0.f;
        #pragma unroll
        for (int g = 0; g < 4; ++g) {
            float4 a0 = sZm[nt][g][0][lane];
            float4 a1 = sZm[nt][g][1][lane];
            zm0.x+=a0.x; zm0.y+=a0.y; zm0.z+=a0.z; zm0.w+=a0.w;
            zm1.x+=a1.x; zm1.y+=a1.y; zm1.z+=a1.z; zm1.w+=a1.w;
            l += sLm[nt][g][lane];
        }
        l += __shfl_xor(l, 16);    // quads hold disjoint key subsets
        l += __shfl_xor(l, 32);
        const float inv = 1.f / l;

        // Wv^T A-frags for this wave's half of d (L2-hot prepass buffer)
        const unsigned short* wvb = (const unsigned short*)(ws + WV_OFF);
        short8 wv_f[2];
        #pragma unroll
        for (int tt = 0; tt < 2; ++tt) {
            const int t = 2*th + tt;
            union { uint4 u4; short8 s; } w0;
            w0.u4 = *(const uint4_a*)(wvb + (16*t + ln15) * 32 + quad * 8);
            wv_f[tt] = w0.s;
        }
        // pack merged Z as bf16 [q(16)][c'(32)]; same-wave LDS round-trip
        unsigned short* sZb = (unsigned short*)&sB4[kg][0];
        floatx4 zv0 = (floatx4){zm0.x, zm0.y, zm0.z, zm0.w};
        floatx4 zv1 = (floatx4){zm1.x, zm1.y, zm1.z, zm1.w};
        *(ushort4_a*)(sZb + ln15*32 + quad*4)      = pack4(zv0);
        *(ushort4_a*)(sZb + ln15*32 + 16 + quad*4) = pack4(zv1);
        union { uint4 u4; short8 s; } zb;
        zb.u4 = sB4[kg][ln15*4 + quad];
        // O^T = Wv^T · Z^T : 2 MFMA (K=32); col=q=ln15, row=d=16t+quad*4+r
        const int qrow = q0 + 16*nt + ln15;
        #pragma unroll
        for (int tt = 0; tt < 2; ++tt) {
            const int t = 2*th + tt;
            floatx4 o = (floatx4){0.f,0.f,0.f,0.f};
            o = MFMA16(wv_f[tt], zb.s, o);
            *(float4_a*)(out + (bT + (size_t)qrow) * Dd + 16*t + quad*4)
                = make_float4(o[0]*inv, o[1]*inv, o[2]*inv, o[3]*inv);
        }
    }
}

// ---------------------------------------------------------------------------
extern "C" void kernel_launch(void* const* d_in, const int* in_sizes, int n_in,
                              void* d_out, int out_size, void* d_ws, size_t ws_size,
                              hipStream_t stream)
{
    const float* x  = (const float*)d_in[0];
    const float* Wk = (const float*)d_in[1];   // setup_inputs order: x, Wk, Wq, Wv
    const float* Wq = (const float*)d_in[2];
    const float* Wv = (const float*)d_in[3];
    float* out = (float*)d_out;

    // Prepass: 1024 blocks x 256 thr (4/CU, fully resident), 32-row slabs.
    prep_kernel<<<1024, 256, 0, stream>>>(x, Wk, Wq, Wv, (char*)d_ws);
    // Main: 1024 blocks (4/CU, fully resident, b==XCD), 256 thr, 22 KB LDS.
    attn_kernel<<<Bc * 128, 256, 0, stream>>>((const char*)d_ws, out);
}